// Round 1
// 309.849 us; speedup vs baseline: 1.0046x; 1.0046x over previous
//
#include <hip/hip_runtime.h>
#include <hip/hip_bf16.h>
#include <math.h>

// Problem constants (fixed by setup_inputs)
#define SEQ    2048
#define BATCH  4
#define XDIM   16
#define DMODEL 256
#define NHEAD  8
#define DH     32
#define DFF    512
#define NLAYER 2
#define MPOS   1024
#define ROWS   (SEQ*BATCH)   // 8192

#define ATT_SCALE 0.17677669529663687f  // 1/sqrt(32)

typedef __attribute__((ext_vector_type(8))) short bf16x8;  // MFMA A/B frag (4 VGPRs)
typedef __attribute__((ext_vector_type(4))) float f32x4;   // MFMA C/D frag

__device__ __forceinline__ float gelu_exact(float x) {
    return 0.5f * x * (1.0f + erff(x * 0.70710678118654752f));
}

// fp32 -> bf16 (round-to-nearest-even), as raw short
__device__ __forceinline__ short f2bf(float f) {
    unsigned int u = __float_as_uint(f);
    u += 0x7FFFu + ((u >> 16) & 1u);
    return (short)(u >> 16);
}
__device__ __forceinline__ float bf2f(unsigned short u) {
    return __uint_as_float(((unsigned int)u) << 16);
}

// async global->LDS, 16B per lane. LDS dest is WAVE-UNIFORM base + lane*16;
// global src is per-lane. __syncthreads() drains vmcnt before the barrier.
__device__ __forceinline__ void gload16(const unsigned short* g, unsigned short* l) {
    __builtin_amdgcn_global_load_lds(
        (const __attribute__((address_space(1))) unsigned int*)g,
        (__attribute__((address_space(3))) unsigned int*)l, 16, 0, 0);
}

// ---------------- encoder + weight casts, ONE launch --------------------------
__global__ __launch_bounds__(256) void encode_cast(
    const float* __restrict__ x, const float* __restrict__ y,
    const float* __restrict__ xw, const float* __restrict__ xb,
    const float* __restrict__ yw, const float* __restrict__ yb,
    float* __restrict__ h, unsigned short* __restrict__ hb,
    const float* __restrict__ s0, const float* __restrict__ s1,
    const float* __restrict__ s2, const float* __restrict__ s3,
    const float* __restrict__ s4,
    unsigned short* __restrict__ d0, unsigned short* __restrict__ d1,
    unsigned short* __restrict__ d2, unsigned short* __restrict__ d3,
    unsigned short* __restrict__ d4)
{
    if (blockIdx.x < ROWS) {
        int row = blockIdx.x;      // s*BATCH + b
        int d   = threadIdx.x;     // 0..255
        int s   = row / BATCH;
        __shared__ float xs[XDIM];
        __shared__ float ys;
        if (d < XDIM) xs[d] = x[(size_t)row*XDIM + d];
        if (d == 0)   ys    = y[row];
        __syncthreads();
        float acc = xb[d];
        #pragma unroll
        for (int k = 0; k < XDIM; ++k) acc = fmaf(xs[k], xw[d*XDIM + k], acc);
        if (s < MPOS) acc += ys * yw[d] + yb[d];
        h[(size_t)row*DMODEL + d]  = acc;
        hb[(size_t)row*DMODEL + d] = (unsigned short)f2bf(acc);
        return;
    }
    int i = (blockIdx.x - ROWS)*256 + threadIdx.x;
    if (i >= 147456) return;
    const float* s; unsigned short* d; int off;
    if      (i <  49152) { s = s0; d = d0; off = i; }
    else if (i <  65536) { s = s1; d = d1; off = i - 49152; }
    else if (i <  98304) { s = s2; d = d2; off = i - 65536; }
    else if (i < 131072) { s = s3; d = d3; off = i - 98304; }
    else                 { s = s4; d = d4; off = i - 131072; }
    float4 a = *(const float4*)(s + (size_t)off*8);
    float4 c = *(const float4*)(s + (size_t)off*8 + 4);
    ushort4 u0, u1;
    u0.x=(unsigned short)f2bf(a.x); u0.y=(unsigned short)f2bf(a.y);
    u0.z=(unsigned short)f2bf(a.z); u0.w=(unsigned short)f2bf(a.w);
    u1.x=(unsigned short)f2bf(c.x); u1.y=(unsigned short)f2bf(c.y);
    u1.z=(unsigned short)f2bf(c.z); u1.w=(unsigned short)f2bf(c.w);
    *(ushort4*)(d + (size_t)off*8)     = u0;
    *(ushort4*)(d + (size_t)off*8 + 4) = u1;
}

// ---------------- bf16 MFMA GEMM 128x128, swapped epilogue (ff1) -------------
// m97 structure: linear [rows][32] LDS + global_load_lds width=16.
#define BK 32
__global__ __launch_bounds__(256) void gemm128(
    const unsigned short* __restrict__ A, const unsigned short* __restrict__ B,
    const float* __restrict__ bias, unsigned short* __restrict__ Cb,
    int N, int K, int doGelu)
{
    __shared__ unsigned short As[128][BK];
    __shared__ unsigned short Bs[128][BK];
    int tid  = threadIdx.x;
    int w    = tid >> 6, lane = tid & 63;
    int col  = lane & 15, quad = lane >> 4;
    int wm   = (w >> 1) * 64, wn = (w & 1) * 64;
    int m0   = blockIdx.y * 128, n0 = blockIdx.x * 128;
    int l4   = lane >> 2, c8 = (lane & 3) * 8;

    f32x4 acc[4][4];
    #pragma unroll
    for (int i = 0; i < 4; ++i)
        #pragma unroll
        for (int j = 0; j < 4; ++j) acc[i][j] = (f32x4){0.f,0.f,0.f,0.f};

    // wave w stages rows [w*32, w*32+32) of each tile (2 instrs of 16 rows)
    const unsigned short* ga = A + (size_t)(m0 + w*32 + l4)*K + c8;
    const unsigned short* gb = B + (size_t)(n0 + w*32 + l4)*K + c8;

    for (int k0 = 0; k0 < K; k0 += BK) {
        __syncthreads();
        gload16(ga + k0,                  &As[w*32     ][0]);
        gload16(ga + k0 + (size_t)16*K,   &As[w*32 + 16][0]);
        gload16(gb + k0,                  &Bs[w*32     ][0]);
        gload16(gb + k0 + (size_t)16*K,   &Bs[w*32 + 16][0]);
        __syncthreads();
        bf16x8 af[4], bfr[4];
        #pragma unroll
        for (int i = 0; i < 4; ++i) af[i]  = *(const bf16x8*)&As[wm + i*16 + col][quad*8];
        #pragma unroll
        for (int j = 0; j < 4; ++j) bfr[j] = *(const bf16x8*)&Bs[wn + j*16 + col][quad*8];
        #pragma unroll
        for (int i = 0; i < 4; ++i)
            #pragma unroll
            for (int j = 0; j < 4; ++j)
                acc[i][j] = __builtin_amdgcn_mfma_f32_16x16x32_bf16(bfr[j], af[i], acc[i][j], 0, 0, 0);
    }

    #pragma unroll
    for (int i = 0; i < 4; ++i) {
        int m = m0 + wm + i*16 + col;
        #pragma unroll
        for (int j = 0; j < 4; ++j) {
            int n = n0 + wn + j*16 + quad*4;
            float4 bi = *(const float4*)&bias[n];
            float v0 = acc[i][j][0] + bi.x, v1 = acc[i][j][1] + bi.y;
            float v2 = acc[i][j][2] + bi.z, v3 = acc[i][j][3] + bi.w;
            if (doGelu) { v0=gelu_exact(v0); v1=gelu_exact(v1); v2=gelu_exact(v2); v3=gelu_exact(v3); }
            ushort4 u;
            u.x=(unsigned short)f2bf(v0); u.y=(unsigned short)f2bf(v1);
            u.z=(unsigned short)f2bf(v2); u.w=(unsigned short)f2bf(v3);
            *(ushort4*)(Cb + (size_t)m*N + n) = u;
        }
    }
}

// ---------------- qkv GEMM with fused K/V re-layout --------------------------
// N=768 fixed; grid (6, ROWS/128). Blocks 0,1 -> Q; 2,3 -> K; 4,5 -> V.
__global__ __launch_bounds__(256) void gemm_qkv(
    const unsigned short* __restrict__ A, const unsigned short* __restrict__ B,
    const float* __restrict__ bias,
    unsigned short* __restrict__ Qg, unsigned short* __restrict__ Kg,
    unsigned short* __restrict__ Vg, int K)
{
    __shared__ unsigned short As[128][BK];
    __shared__ unsigned short Bs[128][BK];
    int tid  = threadIdx.x;
    int w    = tid >> 6, lane = tid & 63;
    int col  = lane & 15, quad = lane >> 4;
    int wm   = (w >> 1) * 64, wn = (w & 1) * 64;
    int m0   = blockIdx.y * 128, n0 = blockIdx.x * 128;
    int l4   = lane >> 2, c8 = (lane & 3) * 8;

    f32x4 acc[4][4];
    #pragma unroll
    for (int i = 0; i < 4; ++i)
        #pragma unroll
        for (int j = 0; j < 4; ++j) acc[i][j] = (f32x4){0.f,0.f,0.f,0.f};

    const unsigned short* ga = A + (size_t)(m0 + w*32 + l4)*K + c8;
    const unsigned short* gb = B + (size_t)(n0 + w*32 + l4)*K + c8;

    for (int k0 = 0; k0 < K; k0 += BK) {
        __syncthreads();
        gload16(ga + k0,                &As[w*32     ][0]);
        gload16(ga + k0 + (size_t)16*K, &As[w*32 + 16][0]);
        gload16(gb + k0,                &Bs[w*32     ][0]);
        gload16(gb + k0 + (size_t)16*K, &Bs[w*32 + 16][0]);
        __syncthreads();
        bf16x8 af[4], bfr[4];
        #pragma unroll
        for (int i = 0; i < 4; ++i) af[i]  = *(const bf16x8*)&As[wm + i*16 + col][quad*8];
        #pragma unroll
        for (int j = 0; j < 4; ++j) bfr[j] = *(const bf16x8*)&Bs[wn + j*16 + col][quad*8];
        #pragma unroll
        for (int i = 0; i < 4; ++i)
            #pragma unroll
            for (int j = 0; j < 4; ++j)
                acc[i][j] = __builtin_amdgcn_mfma_f32_16x16x32_bf16(bfr[j], af[i], acc[i][j], 0, 0, 0);
    }

    int region = n0 >> 8;   // 0=Q, 1=K, 2=V (uniform per block)
    #pragma unroll
    for (int i = 0; i < 4; ++i) {
        int m = m0 + wm + i*16 + col;
        int s = m >> 2, bidx = m & 3;
        #pragma unroll
        for (int j = 0; j < 4; ++j) {
            int ng = n0 + wn + j*16 + quad*4;
            float4 bi = *(const float4*)&bias[ng];
            ushort4 u;
            u.x=(unsigned short)f2bf(acc[i][j][0] + bi.x);
            u.y=(unsigned short)f2bf(acc[i][j][1] + bi.y);
            u.z=(unsigned short)f2bf(acc[i][j][2] + bi.z);
            u.w=(unsigned short)f2bf(acc[i][j][3] + bi.w);
            int np = ng - (region << 8);
            int hh = np >> 5, d = np & 31;
            int bh = bidx*NHEAD + hh;
            if (region == 0)
                *(ushort4*)(Qg + ((size_t)(bh*SEQ + s))*DH + d) = u;
            else if (region == 1)
                *(ushort4*)(Kg + ((size_t)(bh*SEQ + s))*DH + d) = u;
            else {
                Vg[((size_t)(bh*DH + d    ))*SEQ + s] = u.x;
                Vg[((size_t)(bh*DH + d + 1))*SEQ + s] = u.y;
                Vg[((size_t)(bh*DH + d + 2))*SEQ + s] = u.z;
                Vg[((size_t)(bh*DH + d + 3))*SEQ + s] = u.w;
            }
        }
    }
}

// ------- GEMM (N=256) + residual + LayerNorm fused, swapped epilogue ---------
__global__ __launch_bounds__(256) void gemm_ln(
    const unsigned short* __restrict__ A, const unsigned short* __restrict__ B,
    const float* __restrict__ bias, const float* __restrict__ g,
    const float* __restrict__ beta, float* __restrict__ h,
    unsigned short* __restrict__ hb, int K)
{
    __shared__ unsigned short As[32][BK];
    __shared__ unsigned short Bs[256][BK];
    __shared__ float sP[2][32], qP[2][32];
    int tid  = threadIdx.x;
    int w    = tid >> 6, lane = tid & 63;
    int col  = lane & 15, quad = lane >> 4;
    int wr   = w >> 1, wc = w & 1;
    int m0   = blockIdx.x * 32;
    int l4   = lane >> 2, c8 = (lane & 3) * 8;

    f32x4 acc[8];
    #pragma unroll
    for (int j = 0; j < 8; ++j) acc[j] = (f32x4){0.f,0.f,0.f,0.f};

    // A: waves 0,1 stage 16 rows each; B: each wave stages 64 rows (4 instrs)
    const unsigned short* ga = A + (size_t)(m0 + (w & 1)*16 + l4)*K + c8;
    const unsigned short* gb = B + (size_t)(w*64 + l4)*K + c8;

    for (int k0 = 0; k0 < K; k0 += BK) {
        __syncthreads();
        if (w < 2) gload16(ga + k0, &As[(w & 1)*16][0]);
        gload16(gb + k0,                &Bs[w*64     ][0]);
        gload16(gb + k0 + (size_t)16*K, &Bs[w*64 + 16][0]);
        gload16(gb + k0 + (size_t)32*K, &Bs[w*64 + 32][0]);
        gload16(gb + k0 + (size_t)48*K, &Bs[w*64 + 48][0]);
        __syncthreads();
        bf16x8 af = *(const bf16x8*)&As[16*wr + col][quad*8];
        #pragma unroll
        for (int j = 0; j < 8; ++j) {
            bf16x8 bfr = *(const bf16x8*)&Bs[128*wc + j*16 + col][quad*8];
            acc[j] = __builtin_amdgcn_mfma_f32_16x16x32_bf16(bfr, af, acc[j], 0, 0, 0);
        }
    }

    int m = m0 + 16*wr + col;
    float v[8][4];
    float s = 0.f, q = 0.f;
    #pragma unroll
    for (int j = 0; j < 8; ++j) {
        int n = 128*wc + j*16 + quad*4;
        float4 bi = *(const float4*)&bias[n];
        float4 hv = *(const float4*)&h[(size_t)m*DMODEL + n];
        float val0 = acc[j][0] + bi.x + hv.x;
        float val1 = acc[j][1] + bi.y + hv.y;
        float val2 = acc[j][2] + bi.z + hv.z;
        float val3 = acc[j][3] + bi.w + hv.w;
        v[j][0]=val0; v[j][1]=val1; v[j][2]=val2; v[j][3]=val3;
        s += (val0+val1) + (val2+val3);
        q += (val0*val0 + val1*val1) + (val2*val2 + val3*val3);
    }
    s += __shfl_xor(s, 16, 64); s += __shfl_xor(s, 32, 64);
    q += __shfl_xor(q, 16, 64); q += __shfl_xor(q, 32, 64);
    if (quad == 0) { sP[wc][16*wr + col] = s; qP[wc][16*wr + col] = q; }
    __syncthreads();
    float st = sP[0][16*wr + col] + sP[1][16*wr + col];
    float qt = qP[0][16*wr + col] + qP[1][16*wr + col];
    float mu   = st * (1.0f/DMODEL);
    float var  = qt * (1.0f/DMODEL) - mu*mu;
    float rstd = rsqrtf(var + 1e-5f);
    #pragma unroll
    for (int j = 0; j < 8; ++j) {
        int n = 128*wc + j*16 + quad*4;
        float4 gv = *(const float4*)&g[n];
        float4 bv = *(const float4*)&beta[n];
        float4 o;
        o.x = (v[j][0]-mu)*rstd*gv.x + bv.x;
        o.y = (v[j][1]-mu)*rstd*gv.y + bv.y;
        o.z = (v[j][2]-mu)*rstd*gv.z + bv.z;
        o.w = (v[j][3]-mu)*rstd*gv.w + bv.w;
        *(float4*)&h[(size_t)m*DMODEL + n] = o;
        ushort4 u;
        u.x=(unsigned short)f2bf(o.x); u.y=(unsigned short)f2bf(o.y);
        u.z=(unsigned short)f2bf(o.z); u.w=(unsigned short)f2bf(o.w);
        *(ushort4*)(hb + (size_t)m*DMODEL + n) = u;
    }
}

// ------- head: out = gelu(A@W1^T + b1) . w2 + b2, swapped epilogue -----------
__global__ __launch_bounds__(256) void gemm_head(
    const unsigned short* __restrict__ A, const unsigned short* __restrict__ B,
    const float* __restrict__ b1, const float* __restrict__ w2,
    const float* __restrict__ b2, float* __restrict__ out, int K)
{
    __shared__ unsigned short As[16][BK];
    __shared__ unsigned short Bs[512][BK];
    __shared__ float dP[4][16];
    int tid  = threadIdx.x;
    int w    = tid >> 6, lane = tid & 63;
    int col  = lane & 15, quad = lane >> 4;
    int m0   = blockIdx.x * 16;
    int l4   = lane >> 2, c8 = (lane & 3) * 8;

    f32x4 acc[8];
    #pragma unroll
    for (int j = 0; j < 8; ++j) acc[j] = (f32x4){0.f,0.f,0.f,0.f};

    const unsigned short* ga = A + (size_t)(m0 + l4)*K + c8;
    const unsigned short* gb = B + (size_t)(w*128 + l4)*K + c8;

    for (int k0 = 0; k0 < K; k0 += BK) {
        __syncthreads();
        if (w == 0) gload16(ga + k0, &As[0][0]);
        #pragma unroll
        for (int t = 0; t < 8; ++t)
            gload16(gb + k0 + (size_t)(t*16)*K, &Bs[w*128 + t*16][0]);
        __syncthreads();
        bf16x8 af = *(const bf16x8*)&As[col][quad*8];
        #pragma unroll
        for (int j = 0; j < 8; ++j) {
            bf16x8 bfr = *(const bf16x8*)&Bs[128*w + j*16 + col][quad*8];
            acc[j] = __builtin_amdgcn_mfma_f32_16x16x32_bf16(bfr, af, acc[j], 0, 0, 0);
        }
    }

    float s = 0.f;
    #pragma unroll
    for (int j = 0; j < 8; ++j) {
        int n = 128*w + j*16 + quad*4;
        float4 b1v = *(const float4*)&b1[n];
        float4 w2v = *(const float4*)&w2[n];
        s += gelu_exact(acc[j][0] + b1v.x) * w2v.x;
        s += gelu_exact(acc[j][1] + b1v.y) * w2v.y;
        s += gelu_exact(acc[j][2] + b1v.z) * w2v.z;
        s += gelu_exact(acc[j][3] + b1v.w) * w2v.w;
    }
    s += __shfl_xor(s, 16, 64); s += __shfl_xor(s, 32, 64);
    if (quad == 0) dP[w][col] = s;
    __syncthreads();
    if (tid < 16)
        out[m0 + tid] = dP[0][tid] + dP[1][tid] + dP[2][tid] + dP[3][tid] + b2[0];
}

// ---------------- MFMA flash attention, transposed flow ----------------------
// 1D grid with XCD-aware decode: each XCD owns 4 (b,h) pairs so their K/V
// (4 x 256 KB = 1 MB) stays resident in that XCD's 4 MB L2.
__global__ __launch_bounds__(256) void attn_mfma(
    const unsigned short* __restrict__ Qg,
    const unsigned short* __restrict__ Kg,
    const unsigned short* __restrict__ Vg,
    unsigned short* __restrict__ o)           // bf16 [s*B+b][256]
{
    const int id = blockIdx.x;                // 0..1023
    const int sl = id >> 3;
    const int bh = (id & 7) * 4 + (sl >> 5);  // XCD (id&7) gets bh in [4x, 4x+4)
    const int qt = sl & 31;
    const int h  = bh & 7;
    const int b  = bh >> 3;
    const int q0 = qt * 64;
    const int tid  = threadIdx.x;
    const int w    = tid >> 6;
    const int lane = tid & 63;
    const int col  = lane & 15;
    const int quad = lane >> 4;

    __shared__ unsigned short Kt[64][40];     // [key][d]
    __shared__ unsigned short Vt[32][72];     // [d][key]
    __shared__ unsigned short Pt[4][16][72];  // per-wave P [q][key]

    const int q = q0 + 16*w + col;
    bf16x8 qf = *(const bf16x8*)(Qg + ((size_t)(bh*SEQ + q))*DH + quad*8);

    f32x4 O0 = {0.f,0.f,0.f,0.f};
    f32x4 O1 = {0.f,0.f,0.f,0.f};
    float lsum = 0.f;

    const int kRow = tid >> 2, kCh = (tid & 3) * 8;
    const int vD   = tid >> 3, vCh = (tid & 7) * 8;

    const int nT = 16 + ((q0 >= MPOS) ? 1 : 0);
    for (int kt = 0; kt < nT; ++kt) {
        const bool self = (kt == 16);
        const int  k0   = self ? q0 : kt*64;
        __syncthreads();
        *(uint4*)&Kt[kRow][kCh] = *(const uint4*)(Kg + ((size_t)(bh*SEQ + k0 + kRow))*DH + kCh);
        *(uint4*)&Vt[vD][vCh]   = *(const uint4*)(Vg + ((size_t)(bh*DH + vD))*SEQ + k0 + vCh);
        __syncthreads();

        #pragma unroll
        for (int mt = 0; mt < 4; ++mt) {
            bf16x8 kf = *(const bf16x8*)&Kt[mt*16 + col][quad*8];
            f32x4 st = {0.f,0.f,0.f,0.f};
            st = __builtin_amdgcn_mfma_f32_16x16x32_bf16(kf, qf, st, 0, 0, 0);
            ushort4 pw;
            #pragma unroll
            for (int i = 0; i < 4; ++i) {
                float p = __expf(st[i]*ATT_SCALE);
                if (self && (mt*16 + quad*4 + i != 16*w + col)) p = 0.f;
                unsigned short us = (unsigned short)f2bf(p);
                ((unsigned short*)&pw)[i] = us;
                lsum += bf2f(us);
            }
            *(ushort4*)&Pt[w][col][mt*16 + quad*4] = pw;
        }
        #pragma unroll
        for (int c = 0; c < 2; ++c) {
            bf16x8 pf = *(const bf16x8*)&Pt[w][col][c*32 + quad*8];
            bf16x8 v0 = *(const bf16x8*)&Vt[col     ][c*32 + quad*8];
            bf16x8 v1 = *(const bf16x8*)&Vt[col + 16][c*32 + quad*8];
            O0 = __builtin_amdgcn_mfma_f32_16x16x32_bf16(v0, pf, O0, 0, 0, 0);
            O1 = __builtin_amdgcn_mfma_f32_16x16x32_bf16(v1, pf, O1, 0, 0, 0);
        }
    }

    lsum += __shfl_xor(lsum, 16, 64);
    lsum += __shfl_xor(lsum, 32, 64);
    float inv = 1.0f / lsum;
    ushort4 u0, u1;
    #pragma unroll
    for (int i = 0; i < 4; ++i) {
        ((unsigned short*)&u0)[i] = (unsigned short)f2bf(O0[i]*inv);
        ((unsigned short*)&u1)[i] = (unsigned short)f2bf(O1[i]*inv);
    }
    unsigned short* op = o + ((size_t)(q*BATCH + b))*DMODEL + h*DH;
    *(ushort4*)(op + quad*4)      = u0;
    *(ushort4*)(op + 16 + quad*4) = u1;
}

extern "C" void kernel_launch(void* const* d_in, const int* in_sizes, int n_in,
                              void* d_out, int out_size, void* d_ws, size_t ws_size,
                              hipStream_t stream)
{
    const float* x        = (const float*)d_in[0];
    const float* y        = (const float*)d_in[1];
    const float* xenc_w   = (const float*)d_in[3];
    const float* xenc_b   = (const float*)d_in[4];
    const float* yenc_w   = (const float*)d_in[5];
    const float* yenc_b   = (const float*)d_in[6];
    const float* in_proj_w  = (const float*)d_in[7];
    const float* in_proj_b  = (const float*)d_in[8];
    const float* out_proj_w = (const float*)d_in[9];
    const float* out_proj_b = (const float*)d_in[10];
    const float* ln1_g    = (const float*)d_in[11];
    const float* ln1_b    = (const float*)d_in[12];
    const float* lin1_w   = (const float*)d_in[13];
    const float* lin1_b   = (const float*)d_in[14];
    const float* lin2_w   = (const float*)d_in[15];
    const float* lin2_b   = (const float*)d_in[16];
    const float* ln2_g    = (const float*)d_in[17];
    const float* ln2_b    = (const float*)d_in[18];
    const float* head_w1  = (const float*)d_in[19];
    const float* head_b1  = (const float*)d_in[20];
    const float* head_w2  = (const float*)d_in[21];
    const float* head_b2  = (const float*)d_in[22];
    float* out = (float*)d_out;

    // ---- workspace layout ----
    float* ws  = (float*)d_ws;
    float* h    = ws;                                           // 2M f32
    unsigned short* hb    = (unsigned short*)(h + (size_t)ROWS*DMODEL);  // 2M bf16
    unsigned short* ffb   = hb    + (size_t)ROWS*DMODEL;        // 4M bf16
    unsigned short* attb  = ffb   + (size_t)ROWS*DFF;           // 2M bf16
    unsigned short* Qg    = attb  + (size_t)ROWS*DMODEL;        // 2M bf16
    unsigned short* Kg    = Qg    + (size_t)BATCH*NHEAD*SEQ*DH; // 2M bf16
    unsigned short* Vg    = Kg    + (size_t)BATCH*NHEAD*SEQ*DH; // 2M bf16
    unsigned short* Wqkv  = Vg    + (size_t)BATCH*NHEAD*SEQ*DH; // weights bf16
    unsigned short* Wout  = Wqkv  + (size_t)NLAYER*3*DMODEL*DMODEL;
    unsigned short* Wl1   = Wout  + (size_t)NLAYER*DMODEL*DMODEL;
    unsigned short* Wl2   = Wl1   + (size_t)NLAYER*DFF*DMODEL;
    unsigned short* Wh1   = Wl2   + (size_t)NLAYER*DMODEL*DFF;

    encode_cast<<<ROWS + 576, 256, 0, stream>>>(
        x, y, xenc_w, xenc_b, yenc_w, yenc_b, h, hb,
        in_proj_w, out_proj_w, lin1_w, lin2_w, head_w1,
        Wqkv, Wout, Wl1, Wl2, Wh1);

    for (int l = 0; l < NLAYER; ++l) {
        gemm_qkv<<<dim3(6, ROWS/128), 256, 0, stream>>>(
            hb, Wqkv + (size_t)l*3*DMODEL*DMODEL, in_proj_b + l*3*DMODEL,
            Qg, Kg, Vg, DMODEL);
        attn_mfma<<<dim3(SEQ/64 * NHEAD * BATCH), 256, 0, stream>>>(Qg, Kg, Vg, attb);
        gemm_ln<<<ROWS/32, 256, 0, stream>>>(
            attb, Wout + (size_t)l*DMODEL*DMODEL, out_proj_b + l*DMODEL,
            ln1_g + l*DMODEL, ln1_b + l*DMODEL, h, hb, DMODEL);
        gemm128<<<dim3(DFF/128, ROWS/128), 256, 0, stream>>>(
            hb, Wl1 + (size_t)l*DFF*DMODEL, lin1_b + l*DFF,
            ffb, DFF, DMODEL, 1);
        gemm_ln<<<ROWS/32, 256, 0, stream>>>(
            ffb, Wl2 + (size_t)l*DMODEL*DFF, lin2_b + l*DMODEL,
            ln2_g + l*DMODEL, ln2_b + l*DMODEL, h, hb, DFF);
    }

    const int QROWS = (SEQ - MPOS) * BATCH;  // 4096
    gemm_head<<<QROWS/16, 256, 0, stream>>>(
        hb + (size_t)MPOS*BATCH*DMODEL, Wh1, head_b1, head_w2, head_b2, out, DMODEL);
}

// Round 2
// 289.415 us; speedup vs baseline: 1.0756x; 1.0706x over previous
//
#include <hip/hip_runtime.h>
#include <hip/hip_bf16.h>
#include <math.h>

// Problem constants (fixed by setup_inputs)
#define SEQ    2048
#define BATCH  4
#define XDIM   16
#define DMODEL 256
#define NHEAD  8
#define DH     32
#define DFF    512
#define NLAYER 2
#define MPOS   1024
#define ROWS   (SEQ*BATCH)   // 8192

#define ATT_SCALE 0.17677669529663687f  // 1/sqrt(32)

typedef __attribute__((ext_vector_type(8))) short bf16x8;  // MFMA A/B frag (4 VGPRs)
typedef __attribute__((ext_vector_type(4))) float f32x4;   // MFMA C/D frag

__device__ __forceinline__ float gelu_exact(float x) {
    return 0.5f * x * (1.0f + erff(x * 0.70710678118654752f));
}

// fp32 -> bf16 (round-to-nearest-even), as raw short
__device__ __forceinline__ short f2bf(float f) {
    unsigned int u = __float_as_uint(f);
    u += 0x7FFFu + ((u >> 16) & 1u);
    return (short)(u >> 16);
}
__device__ __forceinline__ float bf2f(unsigned short u) {
    return __uint_as_float(((unsigned int)u) << 16);
}

// async global->LDS, 16B per lane. LDS dest is WAVE-UNIFORM base + lane*16.
__device__ __forceinline__ void gload16(const unsigned short* g, unsigned short* l) {
    __builtin_amdgcn_global_load_lds(
        (const __attribute__((address_space(1))) unsigned int*)g,
        (__attribute__((address_space(3))) unsigned int*)l, 16, 0, 0);
}

// ---------------- encoder + weight casts, ONE launch --------------------------
__global__ __launch_bounds__(256) void encode_cast(
    const float* __restrict__ x, const float* __restrict__ y,
    const float* __restrict__ xw, const float* __restrict__ xb,
    const float* __restrict__ yw, const float* __restrict__ yb,
    float* __restrict__ h, unsigned short* __restrict__ hb,
    const float* __restrict__ s0, const float* __restrict__ s1,
    const float* __restrict__ s2, const float* __restrict__ s3,
    const float* __restrict__ s4,
    unsigned short* __restrict__ d0, unsigned short* __restrict__ d1,
    unsigned short* __restrict__ d2, unsigned short* __restrict__ d3,
    unsigned short* __restrict__ d4)
{
    if (blockIdx.x < ROWS) {
        int row = blockIdx.x;      // s*BATCH + b
        int d   = threadIdx.x;     // 0..255
        int s   = row / BATCH;
        __shared__ float xs[XDIM];
        __shared__ float ys;
        if (d < XDIM) xs[d] = x[(size_t)row*XDIM + d];
        if (d == 0)   ys    = y[row];
        __syncthreads();
        float acc = xb[d];
        #pragma unroll
        for (int k = 0; k < XDIM; ++k) acc = fmaf(xs[k], xw[d*XDIM + k], acc);
        if (s < MPOS) acc += ys * yw[d] + yb[d];
        h[(size_t)row*DMODEL + d]  = acc;
        hb[(size_t)row*DMODEL + d] = (unsigned short)f2bf(acc);
        return;
    }
    int i = (blockIdx.x - ROWS)*256 + threadIdx.x;
    if (i >= 147456) return;
    const float* s; unsigned short* d; int off;
    if      (i <  49152) { s = s0; d = d0; off = i; }
    else if (i <  65536) { s = s1; d = d1; off = i - 49152; }
    else if (i <  98304) { s = s2; d = d2; off = i - 65536; }
    else if (i < 131072) { s = s3; d = d3; off = i - 98304; }
    else                 { s = s4; d = d4; off = i - 131072; }
    float4 a = *(const float4*)(s + (size_t)off*8);
    float4 c = *(const float4*)(s + (size_t)off*8 + 4);
    ushort4 u0, u1;
    u0.x=(unsigned short)f2bf(a.x); u0.y=(unsigned short)f2bf(a.y);
    u0.z=(unsigned short)f2bf(a.z); u0.w=(unsigned short)f2bf(a.w);
    u1.x=(unsigned short)f2bf(c.x); u1.y=(unsigned short)f2bf(c.y);
    u1.z=(unsigned short)f2bf(c.z); u1.w=(unsigned short)f2bf(c.w);
    *(ushort4*)(d + (size_t)off*8)     = u0;
    *(ushort4*)(d + (size_t)off*8 + 4) = u1;
}

// ---------------- bf16 MFMA GEMM 128x64, dbuf prefetch (ff1) ------------------
// 1 barrier/K-step; prefetch of step s+1 issued before compute of step s so the
// vmcnt(0) drain at the barrier overlaps MFMA+ds_read. Grid 512 = 2 blocks/CU.
#define BK 32
__global__ __launch_bounds__(256) void gemm128(
    const unsigned short* __restrict__ A, const unsigned short* __restrict__ B,
    const float* __restrict__ bias, unsigned short* __restrict__ Cb,
    int N, int K, int doGelu)
{
    __shared__ unsigned short As[2][128][BK];
    __shared__ unsigned short Bs[2][64][BK];
    int tid  = threadIdx.x;
    int w    = tid >> 6, lane = tid & 63;
    int col  = lane & 15, quad = lane >> 4;
    int m0   = blockIdx.y * 128, n0 = blockIdx.x * 64;
    int l4   = lane >> 2, c8 = (lane & 3) * 8;

    f32x4 acc[2][4];
    #pragma unroll
    for (int i = 0; i < 2; ++i)
        #pragma unroll
        for (int j = 0; j < 4; ++j) acc[i][j] = (f32x4){0.f,0.f,0.f,0.f};

    const unsigned short* ga = A + (size_t)(m0 + w*32 + l4)*K + c8;
    const unsigned short* gb = B + (size_t)(n0 + w*16 + l4)*K + c8;

    // prologue: stage tile 0
    gload16(ga,                 &As[0][w*32     ][0]);
    gload16(ga + (size_t)16*K,  &As[0][w*32 + 16][0]);
    gload16(gb,                 &Bs[0][w*16     ][0]);
    __syncthreads();

    int cur = 0;
    const int NS = K / BK;
    for (int s = 0; s < NS; ++s) {
        if (s + 1 < NS) {
            int k1 = (s + 1) * BK;
            gload16(ga + k1,                &As[cur^1][w*32     ][0]);
            gload16(ga + k1 + (size_t)16*K, &As[cur^1][w*32 + 16][0]);
            gload16(gb + k1,                &Bs[cur^1][w*16     ][0]);
        }
        bf16x8 af[2], bfr[4];
        #pragma unroll
        for (int i = 0; i < 2; ++i) af[i]  = *(const bf16x8*)&As[cur][w*32 + i*16 + col][quad*8];
        #pragma unroll
        for (int j = 0; j < 4; ++j) bfr[j] = *(const bf16x8*)&Bs[cur][j*16 + col][quad*8];
        #pragma unroll
        for (int i = 0; i < 2; ++i)
            #pragma unroll
            for (int j = 0; j < 4; ++j)
                acc[i][j] = __builtin_amdgcn_mfma_f32_16x16x32_bf16(bfr[j], af[i], acc[i][j], 0, 0, 0);
        __syncthreads();
        cur ^= 1;
    }

    #pragma unroll
    for (int i = 0; i < 2; ++i) {
        int m = m0 + w*32 + i*16 + col;
        #pragma unroll
        for (int j = 0; j < 4; ++j) {
            int n = n0 + j*16 + quad*4;
            float4 bi = *(const float4*)&bias[n];
            float v0 = acc[i][j][0] + bi.x, v1 = acc[i][j][1] + bi.y;
            float v2 = acc[i][j][2] + bi.z, v3 = acc[i][j][3] + bi.w;
            if (doGelu) { v0=gelu_exact(v0); v1=gelu_exact(v1); v2=gelu_exact(v2); v3=gelu_exact(v3); }
            ushort4 u;
            u.x=(unsigned short)f2bf(v0); u.y=(unsigned short)f2bf(v1);
            u.z=(unsigned short)f2bf(v2); u.w=(unsigned short)f2bf(v3);
            *(ushort4*)(Cb + (size_t)m*N + n) = u;
        }
    }
}

// ---------------- qkv GEMM 128x64, dbuf, fused K/V re-layout ------------------
// Grid (12, 64) = 768 blocks (3/CU). x-blocks 0-3 -> Q; 4-7 -> K; 8-11 -> V.
// V written via LDS transpose -> coalesced 64B-line stores (was 2B scatter).
__global__ __launch_bounds__(256) void gemm_qkv(
    const unsigned short* __restrict__ A, const unsigned short* __restrict__ B,
    const float* __restrict__ bias,
    unsigned short* __restrict__ Qg, unsigned short* __restrict__ Kg,
    unsigned short* __restrict__ Vg, int K)
{
    __shared__ unsigned short As[2][128][BK];   // 16 KB (reused as transpose buf)
    __shared__ unsigned short Bs[2][64][BK];
    int tid  = threadIdx.x;
    int w    = tid >> 6, lane = tid & 63;
    int col  = lane & 15, quad = lane >> 4;
    int m0   = blockIdx.y * 128, n0 = blockIdx.x * 64;
    int l4   = lane >> 2, c8 = (lane & 3) * 8;

    f32x4 acc[2][4];
    #pragma unroll
    for (int i = 0; i < 2; ++i)
        #pragma unroll
        for (int j = 0; j < 4; ++j) acc[i][j] = (f32x4){0.f,0.f,0.f,0.f};

    const unsigned short* ga = A + (size_t)(m0 + w*32 + l4)*K + c8;
    const unsigned short* gb = B + (size_t)(n0 + w*16 + l4)*K + c8;

    gload16(ga,                 &As[0][w*32     ][0]);
    gload16(ga + (size_t)16*K,  &As[0][w*32 + 16][0]);
    gload16(gb,                 &Bs[0][w*16     ][0]);
    __syncthreads();

    int cur = 0;
    const int NS = K / BK;
    for (int s = 0; s < NS; ++s) {
        if (s + 1 < NS) {
            int k1 = (s + 1) * BK;
            gload16(ga + k1,                &As[cur^1][w*32     ][0]);
            gload16(ga + k1 + (size_t)16*K, &As[cur^1][w*32 + 16][0]);
            gload16(gb + k1,                &Bs[cur^1][w*16     ][0]);
        }
        bf16x8 af[2], bfr[4];
        #pragma unroll
        for (int i = 0; i < 2; ++i) af[i]  = *(const bf16x8*)&As[cur][w*32 + i*16 + col][quad*8];
        #pragma unroll
        for (int j = 0; j < 4; ++j) bfr[j] = *(const bf16x8*)&Bs[cur][j*16 + col][quad*8];
        #pragma unroll
        for (int i = 0; i < 2; ++i)
            #pragma unroll
            for (int j = 0; j < 4; ++j)
                acc[i][j] = __builtin_amdgcn_mfma_f32_16x16x32_bf16(bfr[j], af[i], acc[i][j], 0, 0, 0);
        __syncthreads();
        cur ^= 1;
    }

    int region = n0 >> 8;   // 0=Q, 1=K, 2=V (uniform per block)
    if (region < 2) {
        #pragma unroll
        for (int i = 0; i < 2; ++i) {
            int m = m0 + w*32 + i*16 + col;
            int s = m >> 2, bidx = m & 3;
            #pragma unroll
            for (int j = 0; j < 4; ++j) {
                int ng = n0 + j*16 + quad*4;
                float4 bi = *(const float4*)&bias[ng];
                ushort4 u;
                u.x=(unsigned short)f2bf(acc[i][j][0] + bi.x);
                u.y=(unsigned short)f2bf(acc[i][j][1] + bi.y);
                u.z=(unsigned short)f2bf(acc[i][j][2] + bi.z);
                u.w=(unsigned short)f2bf(acc[i][j][3] + bi.w);
                int np = ng - (region << 8);
                int hh = np >> 5, d = np & 31;
                int bh = bidx*NHEAD + hh;
                if (region == 0)
                    *(ushort4*)(Qg + ((size_t)(bh*SEQ + s))*DH + d) = u;
                else
                    *(ushort4*)(Kg + ((size_t)(bh*SEQ + s))*DH + d) = u;
            }
        }
    } else {
        // transpose buffer T3[ni][bidx][ss]: ni in [0,64), bidx in [0,4), ss in [0,32)
        unsigned short* T3 = (unsigned short*)As;   // 64*4*32*2B = 16 KB
        #pragma unroll
        for (int i = 0; i < 2; ++i) {
            int mi = w*32 + i*16 + col;       // 0..127
            int ss = mi >> 2, bidx = mi & 3;
            #pragma unroll
            for (int j = 0; j < 4; ++j) {
                int ni = j*16 + quad*4;
                float4 bi = *(const float4*)&bias[n0 + ni];
                T3[((ni    )*4 + bidx)*32 + ss] = (unsigned short)f2bf(acc[i][j][0] + bi.x);
                T3[((ni + 1)*4 + bidx)*32 + ss] = (unsigned short)f2bf(acc[i][j][1] + bi.y);
                T3[((ni + 2)*4 + bidx)*32 + ss] = (unsigned short)f2bf(acc[i][j][2] + bi.z);
                T3[((ni + 3)*4 + bidx)*32 + ss] = (unsigned short)f2bf(acc[i][j][3] + bi.w);
            }
        }
        __syncthreads();
        int s0 = m0 >> 2;                     // 32 consecutive s per block
        #pragma unroll
        for (int r = 0; r < 4; ++r) {
            int chunk = tid + 256*r;          // 1024 chunks = 256 lines x 4 parts
            int l = chunk >> 2, p = chunk & 3;
            int d = l & 31, hh_l = (l >> 5) & 1, bidx = l >> 6;
            int ni = hh_l*32 + d;
            int hh = ((n0 & 255) + ni) >> 5;  // global head
            int bh = bidx*NHEAD + hh;
            uint4 val = *(const uint4*)&T3[(ni*4 + bidx)*32 + p*8];
            *(uint4*)(Vg + ((size_t)(bh*DH + d))*SEQ + s0 + p*8) = val;
        }
    }
}

// ------- GEMM (N=256) + residual + LayerNorm fused, 16-row blocks, dbuf ------
// Grid ROWS/16 = 512 blocks (2/CU). Wave w owns n in [64w, 64w+64).
__global__ __launch_bounds__(256) void gemm_ln(
    const unsigned short* __restrict__ A, const unsigned short* __restrict__ B,
    const float* __restrict__ bias, const float* __restrict__ g,
    const float* __restrict__ beta, float* __restrict__ h,
    unsigned short* __restrict__ hb, int K)
{
    __shared__ unsigned short As[2][16][BK];
    __shared__ unsigned short Bs[2][256][BK];
    __shared__ float sP[4][16], qP[4][16];
    int tid  = threadIdx.x;
    int w    = tid >> 6, lane = tid & 63;
    int col  = lane & 15, quad = lane >> 4;
    int m0   = blockIdx.x * 16;
    int l4   = lane >> 2, c8 = (lane & 3) * 8;

    f32x4 acc[4];
    #pragma unroll
    for (int j = 0; j < 4; ++j) acc[j] = (f32x4){0.f,0.f,0.f,0.f};

    const unsigned short* ga = A + (size_t)(m0 + l4)*K + c8;
    const unsigned short* gb = B + (size_t)(w*64 + l4)*K + c8;

    if (w == 0) gload16(ga, &As[0][0][0]);
    #pragma unroll
    for (int rr = 0; rr < 4; ++rr)
        gload16(gb + (size_t)(rr*16)*K, &Bs[0][w*64 + rr*16][0]);
    __syncthreads();

    int cur = 0;
    const int NS = K / BK;
    for (int s = 0; s < NS; ++s) {
        if (s + 1 < NS) {
            int k1 = (s + 1) * BK;
            if (w == 0) gload16(ga + k1, &As[cur^1][0][0]);
            #pragma unroll
            for (int rr = 0; rr < 4; ++rr)
                gload16(gb + k1 + (size_t)(rr*16)*K, &Bs[cur^1][w*64 + rr*16][0]);
        }
        bf16x8 af = *(const bf16x8*)&As[cur][col][quad*8];
        #pragma unroll
        for (int j = 0; j < 4; ++j) {
            bf16x8 bfr = *(const bf16x8*)&Bs[cur][w*64 + j*16 + col][quad*8];
            acc[j] = __builtin_amdgcn_mfma_f32_16x16x32_bf16(bfr, af, acc[j], 0, 0, 0);
        }
        __syncthreads();
        cur ^= 1;
    }

    int m = m0 + col;
    float v[4][4];
    float s = 0.f, q = 0.f;
    #pragma unroll
    for (int j = 0; j < 4; ++j) {
        int n = w*64 + j*16 + quad*4;
        float4 bi = *(const float4*)&bias[n];
        float4 hv = *(const float4*)&h[(size_t)m*DMODEL + n];
        float val0 = acc[j][0] + bi.x + hv.x;
        float val1 = acc[j][1] + bi.y + hv.y;
        float val2 = acc[j][2] + bi.z + hv.z;
        float val3 = acc[j][3] + bi.w + hv.w;
        v[j][0]=val0; v[j][1]=val1; v[j][2]=val2; v[j][3]=val3;
        s += (val0+val1) + (val2+val3);
        q += (val0*val0 + val1*val1) + (val2*val2 + val3*val3);
    }
    s += __shfl_xor(s, 16, 64); s += __shfl_xor(s, 32, 64);
    q += __shfl_xor(q, 16, 64); q += __shfl_xor(q, 32, 64);
    if (quad == 0) { sP[w][col] = s; qP[w][col] = q; }
    __syncthreads();
    float st = sP[0][col] + sP[1][col] + sP[2][col] + sP[3][col];
    float qt = qP[0][col] + qP[1][col] + qP[2][col] + qP[3][col];
    float mu   = st * (1.0f/DMODEL);
    float var  = qt * (1.0f/DMODEL) - mu*mu;
    float rstd = rsqrtf(var + 1e-5f);
    #pragma unroll
    for (int j = 0; j < 4; ++j) {
        int n = w*64 + j*16 + quad*4;
        float4 gv = *(const float4*)&g[n];
        float4 bv = *(const float4*)&beta[n];
        float4 o;
        o.x = (v[j][0]-mu)*rstd*gv.x + bv.x;
        o.y = (v[j][1]-mu)*rstd*gv.y + bv.y;
        o.z = (v[j][2]-mu)*rstd*gv.z + bv.z;
        o.w = (v[j][3]-mu)*rstd*gv.w + bv.w;
        *(float4*)&h[(size_t)m*DMODEL + n] = o;
        ushort4 u;
        u.x=(unsigned short)f2bf(o.x); u.y=(unsigned short)f2bf(o.y);
        u.z=(unsigned short)f2bf(o.z); u.w=(unsigned short)f2bf(o.w);
        *(ushort4*)(hb + (size_t)m*DMODEL + n) = u;
    }
}

// ------- head: out = gelu(A@W1^T + b1) . w2 + b2, swapped epilogue -----------
__global__ __launch_bounds__(256) void gemm_head(
    const unsigned short* __restrict__ A, const unsigned short* __restrict__ B,
    const float* __restrict__ b1, const float* __restrict__ w2,
    const float* __restrict__ b2, float* __restrict__ out, int K)
{
    __shared__ unsigned short As[16][BK];
    __shared__ unsigned short Bs[512][BK];
    __shared__ float dP[4][16];
    int tid  = threadIdx.x;
    int w    = tid >> 6, lane = tid & 63;
    int col  = lane & 15, quad = lane >> 4;
    int m0   = blockIdx.x * 16;
    int l4   = lane >> 2, c8 = (lane & 3) * 8;

    f32x4 acc[8];
    #pragma unroll
    for (int j = 0; j < 8; ++j) acc[j] = (f32x4){0.f,0.f,0.f,0.f};

    const unsigned short* ga = A + (size_t)(m0 + l4)*K + c8;
    const unsigned short* gb = B + (size_t)(w*128 + l4)*K + c8;

    for (int k0 = 0; k0 < K; k0 += BK) {
        __syncthreads();
        if (w == 0) gload16(ga + k0, &As[0][0]);
        #pragma unroll
        for (int t = 0; t < 8; ++t)
            gload16(gb + k0 + (size_t)(t*16)*K, &Bs[w*128 + t*16][0]);
        __syncthreads();
        bf16x8 af = *(const bf16x8*)&As[col][quad*8];
        #pragma unroll
        for (int j = 0; j < 8; ++j) {
            bf16x8 bfr = *(const bf16x8*)&Bs[128*w + j*16 + col][quad*8];
            acc[j] = __builtin_amdgcn_mfma_f32_16x16x32_bf16(bfr, af, acc[j], 0, 0, 0);
        }
    }

    float s = 0.f;
    #pragma unroll
    for (int j = 0; j < 8; ++j) {
        int n = 128*w + j*16 + quad*4;
        float4 b1v = *(const float4*)&b1[n];
        float4 w2v = *(const float4*)&w2[n];
        s += gelu_exact(acc[j][0] + b1v.x) * w2v.x;
        s += gelu_exact(acc[j][1] + b1v.y) * w2v.y;
        s += gelu_exact(acc[j][2] + b1v.z) * w2v.z;
        s += gelu_exact(acc[j][3] + b1v.w) * w2v.w;
    }
    s += __shfl_xor(s, 16, 64); s += __shfl_xor(s, 32, 64);
    if (quad == 0) dP[w][col] = s;
    __syncthreads();
    if (tid < 16)
        out[m0 + tid] = dP[0][tid] + dP[1][tid] + dP[2][tid] + dP[3][tid] + b2[0];
}

// ---------------- MFMA flash attention, transposed flow ----------------------
// XCD-aware decode; T14 prefetch: next tile's K/V loads issued right after the
// current tile is published to LDS, latency hides under QK+softmax+PV.
__global__ __launch_bounds__(256) void attn_mfma(
    const unsigned short* __restrict__ Qg,
    const unsigned short* __restrict__ Kg,
    const unsigned short* __restrict__ Vg,
    unsigned short* __restrict__ o)           // bf16 [s*B+b][256]
{
    const int id = blockIdx.x;                // 0..1023
    const int sl = id >> 3;
    const int bh = (id & 7) * 4 + (sl >> 5);  // XCD (id&7) gets bh in [4x, 4x+4)
    const int qt = sl & 31;
    const int h  = bh & 7;
    const int b  = bh >> 3;
    const int q0 = qt * 64;
    const int tid  = threadIdx.x;
    const int w    = tid >> 6;
    const int lane = tid & 63;
    const int col  = lane & 15;
    const int quad = lane >> 4;

    __shared__ unsigned short Kt[64][40];     // [key][d]
    __shared__ unsigned short Vt[32][72];     // [d][key]
    __shared__ unsigned short Pt[4][16][72];  // per-wave P [q][key]

    const int q = q0 + 16*w + col;
    bf16x8 qf = *(const bf16x8*)(Qg + ((size_t)(bh*SEQ + q))*DH + quad*8);

    f32x4 O0 = {0.f,0.f,0.f,0.f};
    f32x4 O1 = {0.f,0.f,0.f,0.f};
    float lsum = 0.f;

    const int kRow = tid >> 2, kCh = (tid & 3) * 8;
    const int vD   = tid >> 3, vCh = (tid & 7) * 8;

    const int nT = 16 + ((q0 >= MPOS) ? 1 : 0);
    uint4 kreg = *(const uint4*)(Kg + ((size_t)(bh*SEQ + kRow))*DH + kCh);
    uint4 vreg = *(const uint4*)(Vg + ((size_t)(bh*DH + vD))*SEQ + vCh);

    for (int kt = 0; kt < nT; ++kt) {
        const bool self = (kt == 16);
        __syncthreads();
        *(uint4*)&Kt[kRow][kCh] = kreg;
        *(uint4*)&Vt[vD][vCh]   = vreg;
        __syncthreads();
        if (kt + 1 < nT) {
            int kn = (kt + 1 == 16) ? q0 : (kt + 1)*64;
            kreg = *(const uint4*)(Kg + ((size_t)(bh*SEQ + kn + kRow))*DH + kCh);
            vreg = *(const uint4*)(Vg + ((size_t)(bh*DH + vD))*SEQ + kn + vCh);
        }

        #pragma unroll
        for (int mt = 0; mt < 4; ++mt) {
            bf16x8 kf = *(const bf16x8*)&Kt[mt*16 + col][quad*8];
            f32x4 st = {0.f,0.f,0.f,0.f};
            st = __builtin_amdgcn_mfma_f32_16x16x32_bf16(kf, qf, st, 0, 0, 0);
            ushort4 pw;
            #pragma unroll
            for (int i = 0; i < 4; ++i) {
                float p = __expf(st[i]*ATT_SCALE);
                if (self && (mt*16 + quad*4 + i != 16*w + col)) p = 0.f;
                unsigned short us = (unsigned short)f2bf(p);
                ((unsigned short*)&pw)[i] = us;
                lsum += bf2f(us);
            }
            *(ushort4*)&Pt[w][col][mt*16 + quad*4] = pw;
        }
        #pragma unroll
        for (int c = 0; c < 2; ++c) {
            bf16x8 pf = *(const bf16x8*)&Pt[w][col][c*32 + quad*8];
            bf16x8 v0 = *(const bf16x8*)&Vt[col     ][c*32 + quad*8];
            bf16x8 v1 = *(const bf16x8*)&Vt[col + 16][c*32 + quad*8];
            O0 = __builtin_amdgcn_mfma_f32_16x16x32_bf16(v0, pf, O0, 0, 0, 0);
            O1 = __builtin_amdgcn_mfma_f32_16x16x32_bf16(v1, pf, O1, 0, 0, 0);
        }
    }

    lsum += __shfl_xor(lsum, 16, 64);
    lsum += __shfl_xor(lsum, 32, 64);
    float inv = 1.0f / lsum;
    ushort4 u0, u1;
    #pragma unroll
    for (int i = 0; i < 4; ++i) {
        ((unsigned short*)&u0)[i] = (unsigned short)f2bf(O0[i]*inv);
        ((unsigned short*)&u1)[i] = (unsigned short)f2bf(O1[i]*inv);
    }
    unsigned short* op = o + ((size_t)(q*BATCH + b))*DMODEL + h*DH;
    *(ushort4*)(op + quad*4)      = u0;
    *(ushort4*)(op + 16 + quad*4) = u1;
}

extern "C" void kernel_launch(void* const* d_in, const int* in_sizes, int n_in,
                              void* d_out, int out_size, void* d_ws, size_t ws_size,
                              hipStream_t stream)
{
    const float* x        = (const float*)d_in[0];
    const float* y        = (const float*)d_in[1];
    const float* xenc_w   = (const float*)d_in[3];
    const float* xenc_b   = (const float*)d_in[4];
    const float* yenc_w   = (const float*)d_in[5];
    const float* yenc_b   = (const float*)d_in[6];
    const float* in_proj_w  = (const float*)d_in[7];
    const float* in_proj_b  = (const float*)d_in[8];
    const float* out_proj_w = (const float*)d_in[9];
    const float* out_proj_b = (const float*)d_in[10];
    const float* ln1_g    = (const float*)d_in[11];
    const float* ln1_b    = (const float*)d_in[12];
    const float* lin1_w   = (const float*)d_in[13];
    const float* lin1_b   = (const float*)d_in[14];
    const float* lin2_w   = (const float*)d_in[15];
    const float* lin2_b   = (const float*)d_in[16];
    const float* ln2_g    = (const float*)d_in[17];
    const float* ln2_b    = (const float*)d_in[18];
    const float* head_w1  = (const float*)d_in[19];
    const float* head_b1  = (const float*)d_in[20];
    const float* head_w2  = (const float*)d_in[21];
    const float* head_b2  = (const float*)d_in[22];
    float* out = (float*)d_out;

    // ---- workspace layout ----
    float* ws  = (float*)d_ws;
    float* h    = ws;                                           // 2M f32
    unsigned short* hb    = (unsigned short*)(h + (size_t)ROWS*DMODEL);  // 2M bf16
    unsigned short* ffb   = hb    + (size_t)ROWS*DMODEL;        // 4M bf16
    unsigned short* attb  = ffb   + (size_t)ROWS*DFF;           // 2M bf16
    unsigned short* Qg    = attb  + (size_t)ROWS*DMODEL;        // 2M bf16
    unsigned short* Kg    = Qg    + (size_t)BATCH*NHEAD*SEQ*DH; // 2M bf16
    unsigned short* Vg    = Kg    + (size_t)BATCH*NHEAD*SEQ*DH; // 2M bf16
    unsigned short* Wqkv  = Vg    + (size_t)BATCH*NHEAD*SEQ*DH; // weights bf16
    unsigned short* Wout  = Wqkv  + (size_t)NLAYER*3*DMODEL*DMODEL;
    unsigned short* Wl1   = Wout  + (size_t)NLAYER*DMODEL*DMODEL;
    unsigned short* Wl2   = Wl1   + (size_t)NLAYER*DFF*DMODEL;
    unsigned short* Wh1   = Wl2   + (size_t)NLAYER*DMODEL*DFF;

    encode_cast<<<ROWS + 576, 256, 0, stream>>>(
        x, y, xenc_w, xenc_b, yenc_w, yenc_b, h, hb,
        in_proj_w, out_proj_w, lin1_w, lin2_w, head_w1,
        Wqkv, Wout, Wl1, Wl2, Wh1);

    for (int l = 0; l < NLAYER; ++l) {
        gemm_qkv<<<dim3(12, ROWS/128), 256, 0, stream>>>(
            hb, Wqkv + (size_t)l*3*DMODEL*DMODEL, in_proj_b + l*3*DMODEL,
            Qg, Kg, Vg, DMODEL);
        attn_mfma<<<dim3(SEQ/64 * NHEAD * BATCH), 256, 0, stream>>>(Qg, Kg, Vg, attb);
        gemm_ln<<<ROWS/16, 256, 0, stream>>>(
            attb, Wout + (size_t)l*DMODEL*DMODEL, out_proj_b + l*DMODEL,
            ln1_g + l*DMODEL, ln1_b + l*DMODEL, h, hb, DMODEL);
        gemm128<<<dim3(DFF/64, ROWS/128), 256, 0, stream>>>(
            hb, Wl1 + (size_t)l*DFF*DMODEL, lin1_b + l*DFF,
            ffb, DFF, DMODEL, 1);
        gemm_ln<<<ROWS/16, 256, 0, stream>>>(
            ffb, Wl2 + (size_t)l*DMODEL*DFF, lin2_b + l*DMODEL,
            ln2_g + l*DMODEL, ln2_b + l*DMODEL, h, hb, DFF);
    }

    const int QROWS = (SEQ - MPOS) * BATCH;  // 4096
    gemm_head<<<QROWS/16, 256, 0, stream>>>(
        hb + (size_t)MPOS*BATCH*DMODEL, Wh1, head_b1, head_w2, head_b2, out, DMODEL);
}

// Round 3
// 284.357 us; speedup vs baseline: 1.0947x; 1.0178x over previous
//
#include <hip/hip_runtime.h>
#include <hip/hip_bf16.h>
#include <math.h>

// Problem constants (fixed by setup_inputs)
#define SEQ    2048
#define BATCH  4
#define XDIM   16
#define DMODEL 256
#define NHEAD  8
#define DH     32
#define DFF    512
#define NLAYER 2
#define MPOS   1024
#define ROWS   (SEQ*BATCH)   // 8192

#define ATT_SCALE 0.17677669529663687f  // 1/sqrt(32)

typedef __attribute__((ext_vector_type(8))) short bf16x8;  // MFMA A/B frag (4 VGPRs)
typedef __attribute__((ext_vector_type(4))) float f32x4;   // MFMA C/D frag

__device__ __forceinline__ float gelu_exact(float x) {
    return 0.5f * x * (1.0f + erff(x * 0.70710678118654752f));
}

// fp32 -> bf16 (round-to-nearest-even), as raw short
__device__ __forceinline__ short f2bf(float f) {
    unsigned int u = __float_as_uint(f);
    u += 0x7FFFu + ((u >> 16) & 1u);
    return (short)(u >> 16);
}
__device__ __forceinline__ float bf2f(unsigned short u) {
    return __uint_as_float(((unsigned int)u) << 16);
}

// async global->LDS, 16B per lane. LDS dest is WAVE-UNIFORM base + lane*16.
__device__ __forceinline__ void gload16(const unsigned short* g, unsigned short* l) {
    __builtin_amdgcn_global_load_lds(
        (const __attribute__((address_space(1))) unsigned int*)g,
        (__attribute__((address_space(3))) unsigned int*)l, 16, 0, 0);
}

// counted vmcnt wait (T4): batch s must be complete; batch s+1 may stay in flight.
#define VMWAIT(N) asm volatile("s_waitcnt vmcnt(" #N ")" ::: "memory")
// raw workgroup barrier without the __syncthreads() vmcnt(0) drain.
__device__ __forceinline__ void pipe_barrier() {
    __builtin_amdgcn_sched_barrier(0);
    __builtin_amdgcn_s_barrier();
    __builtin_amdgcn_sched_barrier(0);
}

// ---------------- encoder + weight casts, ONE launch --------------------------
__global__ __launch_bounds__(256) void encode_cast(
    const float* __restrict__ x, const float* __restrict__ y,
    const float* __restrict__ xw, const float* __restrict__ xb,
    const float* __restrict__ yw, const float* __restrict__ yb,
    float* __restrict__ h, unsigned short* __restrict__ hb,
    const float* __restrict__ s0, const float* __restrict__ s1,
    const float* __restrict__ s2, const float* __restrict__ s3,
    const float* __restrict__ s4,
    unsigned short* __restrict__ d0, unsigned short* __restrict__ d1,
    unsigned short* __restrict__ d2, unsigned short* __restrict__ d3,
    unsigned short* __restrict__ d4)
{
    if (blockIdx.x < ROWS) {
        int row = blockIdx.x;      // s*BATCH + b
        int d   = threadIdx.x;     // 0..255
        int s   = row / BATCH;
        __shared__ float xs[XDIM];
        __shared__ float ys;
        if (d < XDIM) xs[d] = x[(size_t)row*XDIM + d];
        if (d == 0)   ys    = y[row];
        __syncthreads();
        float acc = xb[d];
        #pragma unroll
        for (int k = 0; k < XDIM; ++k) acc = fmaf(xs[k], xw[d*XDIM + k], acc);
        if (s < MPOS) acc += ys * yw[d] + yb[d];
        h[(size_t)row*DMODEL + d]  = acc;
        hb[(size_t)row*DMODEL + d] = (unsigned short)f2bf(acc);
        return;
    }
    int i = (blockIdx.x - ROWS)*256 + threadIdx.x;
    if (i >= 147456) return;
    const float* s; unsigned short* d; int off;
    if      (i <  49152) { s = s0; d = d0; off = i; }
    else if (i <  65536) { s = s1; d = d1; off = i - 49152; }
    else if (i <  98304) { s = s2; d = d2; off = i - 65536; }
    else if (i < 131072) { s = s3; d = d3; off = i - 98304; }
    else                 { s = s4; d = d4; off = i - 131072; }
    float4 a = *(const float4*)(s + (size_t)off*8);
    float4 c = *(const float4*)(s + (size_t)off*8 + 4);
    ushort4 u0, u1;
    u0.x=(unsigned short)f2bf(a.x); u0.y=(unsigned short)f2bf(a.y);
    u0.z=(unsigned short)f2bf(a.z); u0.w=(unsigned short)f2bf(a.w);
    u1.x=(unsigned short)f2bf(c.x); u1.y=(unsigned short)f2bf(c.y);
    u1.z=(unsigned short)f2bf(c.z); u1.w=(unsigned short)f2bf(c.w);
    *(ushort4*)(d + (size_t)off*8)     = u0;
    *(ushort4*)(d + (size_t)off*8 + 4) = u1;
}

// ---------------- bf16 MFMA GEMM 128x64, 3-buffer 2-deep pipeline (ff1) ------
// Per step: vmcnt(G) [batch s done, batch s+1 in flight], raw barrier, issue
// batch s+2 (buffer safe: all waves past barrier => done reading it), compute.
#define BK 32
__global__ __launch_bounds__(256) void gemm128(
    const unsigned short* __restrict__ A, const unsigned short* __restrict__ B,
    const float* __restrict__ bias, unsigned short* __restrict__ Cb,
    int N, int K, int doGelu)
{
    __shared__ unsigned short As[3][128][BK];
    __shared__ unsigned short Bs[3][64][BK];
    int tid  = threadIdx.x;
    int w    = tid >> 6, lane = tid & 63;
    int col  = lane & 15, quad = lane >> 4;
    int m0   = blockIdx.y * 128, n0 = blockIdx.x * 64;
    int l4   = lane >> 2, c8 = (lane & 3) * 8;

    f32x4 acc[2][4];
    #pragma unroll
    for (int i = 0; i < 2; ++i)
        #pragma unroll
        for (int j = 0; j < 4; ++j) acc[i][j] = (f32x4){0.f,0.f,0.f,0.f};

    const unsigned short* ga = A + (size_t)(m0 + w*32 + l4)*K + c8;
    const unsigned short* gb = B + (size_t)(n0 + w*16 + l4)*K + c8;

    const int NS = K / BK;
    // prologue: issue batches 0 and 1 (G=3 gloads per wave per batch)
    gload16(ga,                  &As[0][w*32     ][0]);
    gload16(ga + (size_t)16*K,   &As[0][w*32 + 16][0]);
    gload16(gb,                  &Bs[0][w*16     ][0]);
    gload16(ga + BK,                  &As[1][w*32     ][0]);
    gload16(ga + BK + (size_t)16*K,   &As[1][w*32 + 16][0]);
    gload16(gb + BK,                  &Bs[1][w*16     ][0]);

    int bcur = 0;
    for (int s = 0; s < NS; ++s) {
        if (s == NS - 1) { VMWAIT(0); } else { VMWAIT(3); }
        pipe_barrier();
        if (s + 2 < NS) {
            int bpre = bcur + 2; if (bpre >= 3) bpre -= 3;
            int k2 = (s + 2) * BK;
            gload16(ga + k2,                &As[bpre][w*32     ][0]);
            gload16(ga + k2 + (size_t)16*K, &As[bpre][w*32 + 16][0]);
            gload16(gb + k2,                &Bs[bpre][w*16     ][0]);
        }
        bf16x8 af[2], bfr[4];
        #pragma unroll
        for (int i = 0; i < 2; ++i) af[i]  = *(const bf16x8*)&As[bcur][w*32 + i*16 + col][quad*8];
        #pragma unroll
        for (int j = 0; j < 4; ++j) bfr[j] = *(const bf16x8*)&Bs[bcur][j*16 + col][quad*8];
        #pragma unroll
        for (int i = 0; i < 2; ++i)
            #pragma unroll
            for (int j = 0; j < 4; ++j)
                acc[i][j] = __builtin_amdgcn_mfma_f32_16x16x32_bf16(bfr[j], af[i], acc[i][j], 0, 0, 0);
        bcur = (bcur == 2) ? 0 : bcur + 1;
    }

    #pragma unroll
    for (int i = 0; i < 2; ++i) {
        int m = m0 + w*32 + i*16 + col;
        #pragma unroll
        for (int j = 0; j < 4; ++j) {
            int n = n0 + j*16 + quad*4;
            float4 bi = *(const float4*)&bias[n];
            float v0 = acc[i][j][0] + bi.x, v1 = acc[i][j][1] + bi.y;
            float v2 = acc[i][j][2] + bi.z, v3 = acc[i][j][3] + bi.w;
            if (doGelu) { v0=gelu_exact(v0); v1=gelu_exact(v1); v2=gelu_exact(v2); v3=gelu_exact(v3); }
            ushort4 u;
            u.x=(unsigned short)f2bf(v0); u.y=(unsigned short)f2bf(v1);
            u.z=(unsigned short)f2bf(v2); u.w=(unsigned short)f2bf(v3);
            *(ushort4*)(Cb + (size_t)m*N + n) = u;
        }
    }
}

// ---------------- qkv GEMM 128x64, 3-buffer 2-deep, fused K/V re-layout ------
__global__ __launch_bounds__(256) void gemm_qkv(
    const unsigned short* __restrict__ A, const unsigned short* __restrict__ B,
    const float* __restrict__ bias,
    unsigned short* __restrict__ Qg, unsigned short* __restrict__ Kg,
    unsigned short* __restrict__ Vg, int K)
{
    __shared__ unsigned short As[3][128][BK];   // 24 KB (reused as transpose buf)
    __shared__ unsigned short Bs[3][64][BK];
    int tid  = threadIdx.x;
    int w    = tid >> 6, lane = tid & 63;
    int col  = lane & 15, quad = lane >> 4;
    int m0   = blockIdx.y * 128, n0 = blockIdx.x * 64;
    int l4   = lane >> 2, c8 = (lane & 3) * 8;

    f32x4 acc[2][4];
    #pragma unroll
    for (int i = 0; i < 2; ++i)
        #pragma unroll
        for (int j = 0; j < 4; ++j) acc[i][j] = (f32x4){0.f,0.f,0.f,0.f};

    const unsigned short* ga = A + (size_t)(m0 + w*32 + l4)*K + c8;
    const unsigned short* gb = B + (size_t)(n0 + w*16 + l4)*K + c8;

    const int NS = K / BK;
    gload16(ga,                  &As[0][w*32     ][0]);
    gload16(ga + (size_t)16*K,   &As[0][w*32 + 16][0]);
    gload16(gb,                  &Bs[0][w*16     ][0]);
    gload16(ga + BK,                  &As[1][w*32     ][0]);
    gload16(ga + BK + (size_t)16*K,   &As[1][w*32 + 16][0]);
    gload16(gb + BK,                  &Bs[1][w*16     ][0]);

    int bcur = 0;
    for (int s = 0; s < NS; ++s) {
        if (s == NS - 1) { VMWAIT(0); } else { VMWAIT(3); }
        pipe_barrier();
        if (s + 2 < NS) {
            int bpre = bcur + 2; if (bpre >= 3) bpre -= 3;
            int k2 = (s + 2) * BK;
            gload16(ga + k2,                &As[bpre][w*32     ][0]);
            gload16(ga + k2 + (size_t)16*K, &As[bpre][w*32 + 16][0]);
            gload16(gb + k2,                &Bs[bpre][w*16     ][0]);
        }
        bf16x8 af[2], bfr[4];
        #pragma unroll
        for (int i = 0; i < 2; ++i) af[i]  = *(const bf16x8*)&As[bcur][w*32 + i*16 + col][quad*8];
        #pragma unroll
        for (int j = 0; j < 4; ++j) bfr[j] = *(const bf16x8*)&Bs[bcur][j*16 + col][quad*8];
        #pragma unroll
        for (int i = 0; i < 2; ++i)
            #pragma unroll
            for (int j = 0; j < 4; ++j)
                acc[i][j] = __builtin_amdgcn_mfma_f32_16x16x32_bf16(bfr[j], af[i], acc[i][j], 0, 0, 0);
        bcur = (bcur == 2) ? 0 : bcur + 1;
    }

    int region = n0 >> 8;   // 0=Q, 1=K, 2=V (uniform per block)
    if (region < 2) {
        #pragma unroll
        for (int i = 0; i < 2; ++i) {
            int m = m0 + w*32 + i*16 + col;
            int s = m >> 2, bidx = m & 3;
            #pragma unroll
            for (int j = 0; j < 4; ++j) {
                int ng = n0 + j*16 + quad*4;
                float4 bi = *(const float4*)&bias[ng];
                ushort4 u;
                u.x=(unsigned short)f2bf(acc[i][j][0] + bi.x);
                u.y=(unsigned short)f2bf(acc[i][j][1] + bi.y);
                u.z=(unsigned short)f2bf(acc[i][j][2] + bi.z);
                u.w=(unsigned short)f2bf(acc[i][j][3] + bi.w);
                int np = ng - (region << 8);
                int hh = np >> 5, d = np & 31;
                int bh = bidx*NHEAD + hh;
                if (region == 0)
                    *(ushort4*)(Qg + ((size_t)(bh*SEQ + s))*DH + d) = u;
                else
                    *(ushort4*)(Kg + ((size_t)(bh*SEQ + s))*DH + d) = u;
            }
        }
    } else {
        __syncthreads();   // all waves done reading As before aliasing it
        // transpose buffer T3[ni][bidx][ss]: ni in [0,64), bidx in [0,4), ss in [0,32)
        unsigned short* T3 = (unsigned short*)As;   // 16 KB needed <= 24 KB
        #pragma unroll
        for (int i = 0; i < 2; ++i) {
            int mi = w*32 + i*16 + col;       // 0..127
            int ss = mi >> 2, bidx = mi & 3;
            #pragma unroll
            for (int j = 0; j < 4; ++j) {
                int ni = j*16 + quad*4;
                float4 bi = *(const float4*)&bias[n0 + ni];
                T3[((ni    )*4 + bidx)*32 + ss] = (unsigned short)f2bf(acc[i][j][0] + bi.x);
                T3[((ni + 1)*4 + bidx)*32 + ss] = (unsigned short)f2bf(acc[i][j][1] + bi.y);
                T3[((ni + 2)*4 + bidx)*32 + ss] = (unsigned short)f2bf(acc[i][j][2] + bi.z);
                T3[((ni + 3)*4 + bidx)*32 + ss] = (unsigned short)f2bf(acc[i][j][3] + bi.w);
            }
        }
        __syncthreads();
        int sBase = m0 >> 2;                  // 32 consecutive s per block
        #pragma unroll
        for (int r = 0; r < 4; ++r) {
            int chunk = tid + 256*r;          // 1024 chunks = 256 lines x 4 parts
            int l = chunk >> 2, p = chunk & 3;
            int d = l & 31, hh_l = (l >> 5) & 1, bidx = l >> 6;
            int ni = hh_l*32 + d;
            int hh = ((n0 & 255) + ni) >> 5;  // global head
            int bh = bidx*NHEAD + hh;
            uint4 val = *(const uint4*)&T3[(ni*4 + bidx)*32 + p*8];
            *(uint4*)(Vg + ((size_t)(bh*DH + d))*SEQ + sBase + p*8) = val;
        }
    }
}

// ------- GEMM (N=256) + residual + LayerNorm fused, 3-buffer 2-deep ----------
// Wave0 stages A (1 gload) + 4 B-gloads (G=5); waves 1-3 stage 4 B-gloads (G=4).
__global__ __launch_bounds__(256) void gemm_ln(
    const unsigned short* __restrict__ A, const unsigned short* __restrict__ B,
    const float* __restrict__ bias, const float* __restrict__ g,
    const float* __restrict__ beta, float* __restrict__ h,
    unsigned short* __restrict__ hb, int K)
{
    __shared__ unsigned short As[3][16][BK];
    __shared__ unsigned short Bs[3][256][BK];
    __shared__ float sP[4][16], qP[4][16];
    int tid  = threadIdx.x;
    int w    = tid >> 6, lane = tid & 63;
    int col  = lane & 15, quad = lane >> 4;
    int m0   = blockIdx.x * 16;
    int l4   = lane >> 2, c8 = (lane & 3) * 8;

    f32x4 acc[4];
    #pragma unroll
    for (int j = 0; j < 4; ++j) acc[j] = (f32x4){0.f,0.f,0.f,0.f};

    const unsigned short* ga = A + (size_t)(m0 + l4)*K + c8;
    const unsigned short* gb = B + (size_t)(w*64 + l4)*K + c8;

    const int NS = K / BK;
    #pragma unroll
    for (int pb = 0; pb < 2; ++pb) {
        int k = pb * BK;
        if (w == 0) gload16(ga + k, &As[pb][0][0]);
        #pragma unroll
        for (int rr = 0; rr < 4; ++rr)
            gload16(gb + k + (size_t)(rr*16)*K, &Bs[pb][w*64 + rr*16][0]);
    }

    int bcur = 0;
    for (int s = 0; s < NS; ++s) {
        if (s == NS - 1)  { VMWAIT(0); }
        else if (w == 0)  { VMWAIT(5); }
        else              { VMWAIT(4); }
        pipe_barrier();
        if (s + 2 < NS) {
            int bpre = bcur + 2; if (bpre >= 3) bpre -= 3;
            int k2 = (s + 2) * BK;
            if (w == 0) gload16(ga + k2, &As[bpre][0][0]);
            #pragma unroll
            for (int rr = 0; rr < 4; ++rr)
                gload16(gb + k2 + (size_t)(rr*16)*K, &Bs[bpre][w*64 + rr*16][0]);
        }
        bf16x8 af = *(const bf16x8*)&As[bcur][col][quad*8];
        #pragma unroll
        for (int j = 0; j < 4; ++j) {
            bf16x8 bfr = *(const bf16x8*)&Bs[bcur][w*64 + j*16 + col][quad*8];
            acc[j] = __builtin_amdgcn_mfma_f32_16x16x32_bf16(bfr, af, acc[j], 0, 0, 0);
        }
        bcur = (bcur == 2) ? 0 : bcur + 1;
    }

    int m = m0 + col;
    float v[4][4];
    float s = 0.f, q = 0.f;
    #pragma unroll
    for (int j = 0; j < 4; ++j) {
        int n = w*64 + j*16 + quad*4;
        float4 bi = *(const float4*)&bias[n];
        float4 hv = *(const float4*)&h[(size_t)m*DMODEL + n];
        float val0 = acc[j][0] + bi.x + hv.x;
        float val1 = acc[j][1] + bi.y + hv.y;
        float val2 = acc[j][2] + bi.z + hv.z;
        float val3 = acc[j][3] + bi.w + hv.w;
        v[j][0]=val0; v[j][1]=val1; v[j][2]=val2; v[j][3]=val3;
        s += (val0+val1) + (val2+val3);
        q += (val0*val0 + val1*val1) + (val2*val2 + val3*val3);
    }
    s += __shfl_xor(s, 16, 64); s += __shfl_xor(s, 32, 64);
    q += __shfl_xor(q, 16, 64); q += __shfl_xor(q, 32, 64);
    if (quad == 0) { sP[w][col] = s; qP[w][col] = q; }
    __syncthreads();
    float st = sP[0][col] + sP[1][col] + sP[2][col] + sP[3][col];
    float qt = qP[0][col] + qP[1][col] + qP[2][col] + qP[3][col];
    float mu   = st * (1.0f/DMODEL);
    float var  = qt * (1.0f/DMODEL) - mu*mu;
    float rstd = rsqrtf(var + 1e-5f);
    #pragma unroll
    for (int j = 0; j < 4; ++j) {
        int n = w*64 + j*16 + quad*4;
        float4 gv = *(const float4*)&g[n];
        float4 bv = *(const float4*)&beta[n];
        float4 o;
        o.x = (v[j][0]-mu)*rstd*gv.x + bv.x;
        o.y = (v[j][1]-mu)*rstd*gv.y + bv.y;
        o.z = (v[j][2]-mu)*rstd*gv.z + bv.z;
        o.w = (v[j][3]-mu)*rstd*gv.w + bv.w;
        *(float4*)&h[(size_t)m*DMODEL + n] = o;
        ushort4 u;
        u.x=(unsigned short)f2bf(o.x); u.y=(unsigned short)f2bf(o.y);
        u.z=(unsigned short)f2bf(o.z); u.w=(unsigned short)f2bf(o.w);
        *(ushort4*)(hb + (size_t)m*DMODEL + n) = u;
    }
}

// ------- head: out = gelu(A@W1^T + b1) . w2 + b2, 3-buffer 2-deep ------------
// Wave0 G=9 (1 A + 8 B), waves 1-3 G=8.
__global__ __launch_bounds__(256) void gemm_head(
    const unsigned short* __restrict__ A, const unsigned short* __restrict__ B,
    const float* __restrict__ b1, const float* __restrict__ w2,
    const float* __restrict__ b2, float* __restrict__ out, int K)
{
    __shared__ unsigned short As[3][16][BK];
    __shared__ unsigned short Bs[3][512][BK];
    __shared__ float dP[4][16];
    int tid  = threadIdx.x;
    int w    = tid >> 6, lane = tid & 63;
    int col  = lane & 15, quad = lane >> 4;
    int m0   = blockIdx.x * 16;
    int l4   = lane >> 2, c8 = (lane & 3) * 8;

    f32x4 acc[8];
    #pragma unroll
    for (int j = 0; j < 8; ++j) acc[j] = (f32x4){0.f,0.f,0.f,0.f};

    const unsigned short* ga = A + (size_t)(m0 + l4)*K + c8;
    const unsigned short* gb = B + (size_t)(w*128 + l4)*K + c8;

    const int NS = K / BK;
    #pragma unroll
    for (int pb = 0; pb < 2; ++pb) {
        int k = pb * BK;
        if (w == 0) gload16(ga + k, &As[pb][0][0]);
        #pragma unroll
        for (int t = 0; t < 8; ++t)
            gload16(gb + k + (size_t)(t*16)*K, &Bs[pb][w*128 + t*16][0]);
    }

    int bcur = 0;
    for (int s = 0; s < NS; ++s) {
        if (s == NS - 1)  { VMWAIT(0); }
        else if (w == 0)  { VMWAIT(9); }
        else              { VMWAIT(8); }
        pipe_barrier();
        if (s + 2 < NS) {
            int bpre = bcur + 2; if (bpre >= 3) bpre -= 3;
            int k2 = (s + 2) * BK;
            if (w == 0) gload16(ga + k2, &As[bpre][0][0]);
            #pragma unroll
            for (int t = 0; t < 8; ++t)
                gload16(gb + k2 + (size_t)(t*16)*K, &Bs[bpre][w*128 + t*16][0]);
        }
        bf16x8 af = *(const bf16x8*)&As[bcur][col][quad*8];
        #pragma unroll
        for (int j = 0; j < 8; ++j) {
            bf16x8 bfr = *(const bf16x8*)&Bs[bcur][128*w + j*16 + col][quad*8];
            acc[j] = __builtin_amdgcn_mfma_f32_16x16x32_bf16(bfr, af, acc[j], 0, 0, 0);
        }
        bcur = (bcur == 2) ? 0 : bcur + 1;
    }

    float s = 0.f;
    #pragma unroll
    for (int j = 0; j < 8; ++j) {
        int n = 128*w + j*16 + quad*4;
        float4 b1v = *(const float4*)&b1[n];
        float4 w2v = *(const float4*)&w2[n];
        s += gelu_exact(acc[j][0] + b1v.x) * w2v.x;
        s += gelu_exact(acc[j][1] + b1v.y) * w2v.y;
        s += gelu_exact(acc[j][2] + b1v.z) * w2v.z;
        s += gelu_exact(acc[j][3] + b1v.w) * w2v.w;
    }
    s += __shfl_xor(s, 16, 64); s += __shfl_xor(s, 32, 64);
    if (quad == 0) dP[w][col] = s;
    __syncthreads();
    if (tid < 16)
        out[m0 + tid] = dP[0][tid] + dP[1][tid] + dP[2][tid] + dP[3][tid] + b2[0];
}

// ---------------- MFMA flash attention, transposed flow ----------------------
// XCD-aware decode; K/V double-buffered in LDS -> ONE barrier per tile; T14
// prefetch of next tile's K/V into regs right after the barrier.
__global__ __launch_bounds__(256) void attn_mfma(
    const unsigned short* __restrict__ Qg,
    const unsigned short* __restrict__ Kg,
    const unsigned short* __restrict__ Vg,
    unsigned short* __restrict__ o)           // bf16 [s*B+b][256]
{
    const int id = blockIdx.x;                // 0..1023
    const int sl = id >> 3;
    const int bh = (id & 7) * 4 + (sl >> 5);  // XCD (id&7) gets bh in [4x, 4x+4)
    const int qt = sl & 31;
    const int h  = bh & 7;
    const int b  = bh >> 3;
    const int q0 = qt * 64;
    const int tid  = threadIdx.x;
    const int w    = tid >> 6;
    const int lane = tid & 63;
    const int col  = lane & 15;
    const int quad = lane >> 4;

    __shared__ unsigned short Kt[2][64][40];  // [key][d]
    __shared__ unsigned short Vt[2][32][72];  // [d][key]
    __shared__ unsigned short Pt[4][16][72];  // per-wave P [q][key]

    const int q = q0 + 16*w + col;
    bf16x8 qf = *(const bf16x8*)(Qg + ((size_t)(bh*SEQ + q))*DH + quad*8);

    f32x4 O0 = {0.f,0.f,0.f,0.f};
    f32x4 O1 = {0.f,0.f,0.f,0.f};
    float lsum = 0.f;

    const int kRow = tid >> 2, kCh = (tid & 3) * 8;
    const int vD   = tid >> 3, vCh = (tid & 7) * 8;

    const int nT = 16 + ((q0 >= MPOS) ? 1 : 0);
    uint4 kreg = *(const uint4*)(Kg + ((size_t)(bh*SEQ + kRow))*DH + kCh);
    uint4 vreg = *(const uint4*)(Vg + ((size_t)(bh*DH + vD))*SEQ + vCh);

    for (int kt = 0; kt < nT; ++kt) {
        const bool self = (kt == 16);
        const int  p    = kt & 1;
        *(uint4*)&Kt[p][kRow][kCh] = kreg;
        *(uint4*)&Vt[p][vD][vCh]   = vreg;
        __syncthreads();
        if (kt + 1 < nT) {
            int kn = (kt + 1 == 16) ? q0 : (kt + 1)*64;
            kreg = *(const uint4*)(Kg + ((size_t)(bh*SEQ + kn + kRow))*DH + kCh);
            vreg = *(const uint4*)(Vg + ((size_t)(bh*DH + vD))*SEQ + kn + vCh);
        }

        #pragma unroll
        for (int mt = 0; mt < 4; ++mt) {
            bf16x8 kf = *(const bf16x8*)&Kt[p][mt*16 + col][quad*8];
            f32x4 st = {0.f,0.f,0.f,0.f};
            st = __builtin_amdgcn_mfma_f32_16x16x32_bf16(kf, qf, st, 0, 0, 0);
            ushort4 pw;
            #pragma unroll
            for (int i = 0; i < 4; ++i) {
                float pv = __expf(st[i]*ATT_SCALE);
                if (self && (mt*16 + quad*4 + i != 16*w + col)) pv = 0.f;
                unsigned short us = (unsigned short)f2bf(pv);
                ((unsigned short*)&pw)[i] = us;
                lsum += bf2f(us);
            }
            *(ushort4*)&Pt[w][col][mt*16 + quad*4] = pw;
        }
        #pragma unroll
        for (int c = 0; c < 2; ++c) {
            bf16x8 pf = *(const bf16x8*)&Pt[w][col][c*32 + quad*8];
            bf16x8 v0 = *(const bf16x8*)&Vt[p][col     ][c*32 + quad*8];
            bf16x8 v1 = *(const bf16x8*)&Vt[p][col + 16][c*32 + quad*8];
            O0 = __builtin_amdgcn_mfma_f32_16x16x32_bf16(v0, pf, O0, 0, 0, 0);
            O1 = __builtin_amdgcn_mfma_f32_16x16x32_bf16(v1, pf, O1, 0, 0, 0);
        }
    }

    lsum += __shfl_xor(lsum, 16, 64);
    lsum += __shfl_xor(lsum, 32, 64);
    float inv = 1.0f / lsum;
    ushort4 u0, u1;
    #pragma unroll
    for (int i = 0; i < 4; ++i) {
        ((unsigned short*)&u0)[i] = (unsigned short)f2bf(O0[i]*inv);
        ((unsigned short*)&u1)[i] = (unsigned short)f2bf(O1[i]*inv);
    }
    unsigned short* op = o + ((size_t)(q*BATCH + b))*DMODEL + h*DH;
    *(ushort4*)(op + quad*4)      = u0;
    *(ushort4*)(op + 16 + quad*4) = u1;
}

extern "C" void kernel_launch(void* const* d_in, const int* in_sizes, int n_in,
                              void* d_out, int out_size, void* d_ws, size_t ws_size,
                              hipStream_t stream)
{
    const float* x        = (const float*)d_in[0];
    const float* y        = (const float*)d_in[1];
    const float* xenc_w   = (const float*)d_in[3];
    const float* xenc_b   = (const float*)d_in[4];
    const float* yenc_w   = (const float*)d_in[5];
    const float* yenc_b   = (const float*)d_in[6];
    const float* in_proj_w  = (const float*)d_in[7];
    const float* in_proj_b  = (const float*)d_in[8];
    const float* out_proj_w = (const float*)d_in[9];
    const float* out_proj_b = (const float*)d_in[10];
    const float* ln1_g    = (const float*)d_in[11];
    const float* ln1_b    = (const float*)d_in[12];
    const float* lin1_w   = (const float*)d_in[13];
    const float* lin1_b   = (const float*)d_in[14];
    const float* lin2_w   = (const float*)d_in[15];
    const float* lin2_b   = (const float*)d_in[16];
    const float* ln2_g    = (const float*)d_in[17];
    const float* ln2_b    = (const float*)d_in[18];
    const float* head_w1  = (const float*)d_in[19];
    const float* head_b1  = (const float*)d_in[20];
    const float* head_w2  = (const float*)d_in[21];
    const float* head_b2  = (const float*)d_in[22];
    float* out = (float*)d_out;

    // ---- workspace layout ----
    float* ws  = (float*)d_ws;
    float* h    = ws;                                           // 2M f32
    unsigned short* hb    = (unsigned short*)(h + (size_t)ROWS*DMODEL);  // 2M bf16
    unsigned short* ffb   = hb    + (size_t)ROWS*DMODEL;        // 4M bf16
    unsigned short* attb  = ffb   + (size_t)ROWS*DFF;           // 2M bf16
    unsigned short* Qg    = attb  + (size_t)ROWS*DMODEL;        // 2M bf16
    unsigned short* Kg    = Qg    + (size_t)BATCH*NHEAD*SEQ*DH; // 2M bf16
    unsigned short* Vg    = Kg    + (size_t)BATCH*NHEAD*SEQ*DH; // 2M bf16
    unsigned short* Wqkv  = Vg    + (size_t)BATCH*NHEAD*SEQ*DH; // weights bf16
    unsigned short* Wout  = Wqkv  + (size_t)NLAYER*3*DMODEL*DMODEL;
    unsigned short* Wl1   = Wout  + (size_t)NLAYER*DMODEL*DMODEL;
    unsigned short* Wl2   = Wl1   + (size_t)NLAYER*DFF*DMODEL;
    unsigned short* Wh1   = Wl2   + (size_t)NLAYER*DMODEL*DFF;

    encode_cast<<<ROWS + 576, 256, 0, stream>>>(
        x, y, xenc_w, xenc_b, yenc_w, yenc_b, h, hb,
        in_proj_w, out_proj_w, lin1_w, lin2_w, head_w1,
        Wqkv, Wout, Wl1, Wl2, Wh1);

    for (int l = 0; l < NLAYER; ++l) {
        gemm_qkv<<<dim3(12, ROWS/128), 256, 0, stream>>>(
            hb, Wqkv + (size_t)l*3*DMODEL*DMODEL, in_proj_b + l*3*DMODEL,
            Qg, Kg, Vg, DMODEL);
        attn_mfma<<<dim3(SEQ/64 * NHEAD * BATCH), 256, 0, stream>>>(Qg, Kg, Vg, attb);
        gemm_ln<<<ROWS/16, 256, 0, stream>>>(
            attb, Wout + (size_t)l*DMODEL*DMODEL, out_proj_b + l*DMODEL,
            ln1_g + l*DMODEL, ln1_b + l*DMODEL, h, hb, DMODEL);
        gemm128<<<dim3(DFF/64, ROWS/128), 256, 0, stream>>>(
            hb, Wl1 + (size_t)l*DFF*DMODEL, lin1_b + l*DFF,
            ffb, DFF, DMODEL, 1);
        gemm_ln<<<ROWS/16, 256, 0, stream>>>(
            ffb, Wl2 + (size_t)l*DMODEL*DFF, lin2_b + l*DMODEL,
            ln2_g + l*DMODEL, ln2_b + l*DMODEL, h, hb, DFF);
    }

    const int QROWS = (SEQ - MPOS) * BATCH;  // 4096
    gemm_head<<<QROWS/16, 256, 0, stream>>>(
        hb + (size_t)MPOS*BATCH*DMODEL, Wh1, head_b1, head_w2, head_b2, out, DMODEL);
}